// Round 1
// 553.755 us; speedup vs baseline: 1.4169x; 1.4169x over previous
//
#include <hip/hip_runtime.h>

// Problem constants
constexpr int Nn = 4096, Fc = 128;
constexpr int Rr = 32, Hh = 4, Dd = 32;
constexpr int BT = 96;                          // B*T
constexpr float SCALE = 0.17677669529663687f;   // 1/sqrt(32)

// Workspace layout (float offsets)
constexpr size_t OFF_V1  = 0;                               // [BT][H][R][D] f32   393216
constexpr size_t OFF_Z   = (size_t)BT * Hh * Rr * Dd;       // [BT][H][R]   f32    12288
constexpr size_t OFF_BQK = OFF_Z + (size_t)BT * Hh * Rr;    // [H*R]        f32      128
constexpr size_t OFF_V1Z = OFF_BQK + 128;                   // [BT][H][D][R] bf16 (393216 us = 196608 f)
constexpr size_t OFF_U   = OFF_V1Z + (size_t)BT * Hh * Dd * Rr / 2;  // param bf16 region

// U (ushort) offsets: WK hi (fused key·Wq), Wv hi, Wv lo
constexpr int U_WKHI = 0, U_WVHI = 16384, U_WVLO = 32768;   // 49152 ushorts total

using short8  = __attribute__((ext_vector_type(8))) short;
using floatx4 = __attribute__((ext_vector_type(4))) float;

__device__ inline ushort f2bf(float f) {
    union { float f; unsigned u; } c{f};
    unsigned r = c.u + 0x7fffu + ((c.u >> 16) & 1u);  // RNE
    return (ushort)(r >> 16);
}
__device__ inline float bf2f(ushort u) {
    union { unsigned u; float f; } c{(unsigned)u << 16};
    return c.f;
}

// ---------------------------------------------------------------------------
// kprep: WK[h*32+r][f] = sum_d Wq[h*32+d][f]*key[r][h][d]  (bf16 hi)
//        Wv hi/lo split; bqk[h*32+r] = sum_d bq[h*32+d]*key[r][h][d] (f32)
// attn is linear in x, so key.Wq fuses into one 128x128 weight: kills the
// q GEMM + q LDS roundtrip in both big passes.
// ---------------------------------------------------------------------------
__global__ void kprep(const float* __restrict__ Wq, const float* __restrict__ bq,
                      const float* __restrict__ Wv, const float* __restrict__ key,
                      ushort* __restrict__ U, float* __restrict__ bqk)
{
    const int idx = blockIdx.x * 256 + threadIdx.x;
    if (idx < 16384) {
        const int hr = idx >> 7, f = idx & 127;
        const int h = hr >> 5, r = hr & 31;
        float s = 0.f;
#pragma unroll
        for (int d = 0; d < 32; d++)
            s += Wq[(h * 32 + d) * 128 + f] * key[(r * 4 + h) * 32 + d];
        U[U_WKHI + idx] = f2bf(s);
    } else if (idx < 32768) {
        const int o = idx - 16384;
        const float v = Wv[o];
        const ushort h = f2bf(v);
        U[U_WVHI + o] = h;
        U[U_WVLO + o] = f2bf(v - bf2f(h));
    } else if (idx < 32768 + 128) {
        const int hr = idx - 32768;
        const int h = hr >> 5, r = hr & 31;
        float s = 0.f;
#pragma unroll
        for (int d = 0; d < 32; d++)
            s += bq[h * 32 + d] * key[(r * 4 + h) * 32 + d];
        bqk[hr] = s;
    }
}

// ---------------------------------------------------------------------------
// ka (pass A): per 64-node tile, wave w = head w:
//   attn = x@WK^T + bqk (plain bf16 MFMA), expa = exp(attn*SCALE)
//   xv   = x@Wv^T + bv  (plain bf16 MFMA)
//   row-softmax 1/sum folded into xv; v1 += expa^T @ (xv*srw) via MFMA
//   Z    += colsum(expa)
// Writes ONLY v1/Z atomics (~30 MB) — expa/xv never touch HBM.
// All precision here feeds v2, which is scaled by sigmoid(beta)~0.0099 in the
// output, so plain bf16 (1e-2 rel worst) contributes ~1e-4 absolute. Safe.
// 4 tiles/block => 6.3M atomics total (same as old k2, proven fine).
// ---------------------------------------------------------------------------
__global__ __launch_bounds__(256, 3)
void ka(const float* __restrict__ x, const float* __restrict__ bv,
        const ushort* __restrict__ U, const float* __restrict__ bqk,
        float* __restrict__ v1, float* __restrict__ Z)
{
    // xh [64][136] bf16 17408 B | per-wave: eT [32][72] 4608 B, xvT [32][72] 4608 B
    __shared__ __align__(16) char lds[54272];
    ushort* xh = (ushort*)lds;

    const int t = threadIdx.x;
    const int w = t >> 6, lane = t & 63;
    const int quad = lane >> 4, l15 = lane & 15;
    const int bt = blockIdx.y;

    char* wsc = lds + 17408 + w * 9216;
    ushort* eT  = (ushort*)wsc;           // [32 r][72 n-pad] bf16 (transposed expa)
    ushort* xvT = (ushort*)(wsc + 4608);  // [32 d][72 n-pad] bf16 (xv * srw, transposed)

    const ushort* WKh = U + U_WKHI;
    const ushort* Wvh = U + U_WVHI;

    float bvv[2], bqkv[2];
#pragma unroll
    for (int i = 0; i < 2; i++) {
        bvv[i]  = bv[32 * w + 16 * i + l15];
        bqkv[i] = bqk[32 * w + 16 * i + l15];
    }

    floatx4 accV1[2][2];
#pragma unroll
    for (int i = 0; i < 2; i++)
#pragma unroll
        for (int j = 0; j < 2; j++) accV1[i][j] = (floatx4)0.f;
    float zacc[2] = {0.f, 0.f};

#pragma unroll 1
    for (int it = 0; it < 4; it++) {
        const int n0 = (blockIdx.x * 4 + it) * 64;
        __syncthreads();   // all waves done reading previous xh
        const float4* xg = (const float4*)(x + ((size_t)bt * Nn + n0) * Fc);
#pragma unroll
        for (int i = 0; i < 8; i++) {
            const int idx = i * 256 + t;
            const int row = idx >> 5, c4 = idx & 31;
            float4 v = xg[idx];
            ushort4 hv;
            hv.x = f2bf(v.x); hv.y = f2bf(v.y); hv.z = f2bf(v.z); hv.w = f2bf(v.w);
            *(ushort4*)&xh[row * 136 + c4 * 4] = hv;
        }
        __syncthreads();

        floatx4 acca[4][2], accv[4][2];
#pragma unroll
        for (int mt = 0; mt < 4; mt++)
#pragma unroll
            for (int nt = 0; nt < 2; nt++) {
                acca[mt][nt] = (floatx4)0.f;
                accv[mt][nt] = (floatx4)0.f;
            }

#pragma unroll
        for (int kc = 0; kc < 4; kc++) {
            short8 ah[4];
#pragma unroll
            for (int mt = 0; mt < 4; mt++)
                ah[mt] = *(const short8*)&xh[(16 * mt + l15) * 136 + kc * 32 + quad * 8];
            short8 kb2[2], vb[2];
#pragma unroll
            for (int nt = 0; nt < 2; nt++) {
                const int off = (32 * w + 16 * nt + l15) * 128 + kc * 32 + quad * 8;
                kb2[nt] = *(const short8*)&WKh[off];
                vb[nt]  = *(const short8*)&Wvh[off];
            }
#pragma unroll
            for (int mt = 0; mt < 4; mt++)
#pragma unroll
                for (int nt = 0; nt < 2; nt++) {
                    acca[mt][nt] = __builtin_amdgcn_mfma_f32_16x16x32_bf16(ah[mt], kb2[nt], acca[mt][nt], 0, 0, 0);
                    accv[mt][nt] = __builtin_amdgcn_mfma_f32_16x16x32_bf16(ah[mt], vb[nt],  accv[mt][nt], 0, 0, 0);
                }
        }

        // expa -> eT [r][n] bf16 (transposed scatter); Z partials in regs.
        // (per-wave LDS: DS ops in-order per wave, no syncthreads needed)
#pragma unroll
        for (int mt = 0; mt < 4; mt++)
#pragma unroll
            for (int rt = 0; rt < 2; rt++)
#pragma unroll
                for (int reg = 0; reg < 4; reg++) {
                    const int row = 16 * mt + 4 * quad + reg;  // n
                    const float e = __expf((acca[mt][rt][reg] + bqkv[rt]) * SCALE);
                    eT[(16 * rt + l15) * 72 + row] = f2bf(e);
                    zacc[rt] += e;
                }

        // row sums: lane <-> node (uses bf16 values == MFMA numerator: consistent)
        float s = 0.f;
#pragma unroll
        for (int r = 0; r < 32; r++) s += bf2f(eT[r * 72 + lane]);
        const float sinv = 1.f / s;

        // xv -> xvT [d][n] bf16, pre-scaled by srw[n] (softmax normalization
        // folded into the B operand; srw broadcast via bpermute, no LDS)
#pragma unroll
        for (int mt = 0; mt < 4; mt++)
#pragma unroll
            for (int reg = 0; reg < 4; reg++) {
                const int row = 16 * mt + 4 * quad + reg;      // n
                const float sw = __shfl(sinv, row);
#pragma unroll
                for (int nt = 0; nt < 2; nt++) {
                    const float v = (accv[mt][nt][reg] + bvv[nt]) * sw;
                    xvT[(16 * nt + l15) * 72 + row] = f2bf(v);
                }
            }

        // v1[r][d] += sum_n eT[r][n] * xvT[d][n]   (A=[r][n], B stored [d][n])
#pragma unroll
        for (int kn = 0; kn < 2; kn++) {
            short8 ae[2], bx[2];
#pragma unroll
            for (int i = 0; i < 2; i++) {
                ae[i] = *(const short8*)&eT[(16 * i + l15) * 72 + kn * 32 + quad * 8];
                bx[i] = *(const short8*)&xvT[(16 * i + l15) * 72 + kn * 32 + quad * 8];
            }
#pragma unroll
            for (int mt = 0; mt < 2; mt++)
#pragma unroll
                for (int nt = 0; nt < 2; nt++)
                    accV1[mt][nt] = __builtin_amdgcn_mfma_f32_16x16x32_bf16(ae[mt], bx[nt], accV1[mt][nt], 0, 0, 0);
        }
    }

    // Z: reduce over quads (rows partitioned by quad), atomic once per col
#pragma unroll
    for (int rt = 0; rt < 2; rt++) {
        float zr = zacc[rt];
        zr += __shfl_xor(zr, 16);
        zr += __shfl_xor(zr, 32);
        if (quad == 0)
            atomicAdd(&Z[((size_t)bt * Hh + w) * Rr + 16 * rt + l15], zr);
    }
    // v1 atomics (C-layout: row r = 16mt+4quad+reg, col d = 16nt+l15)
    float* v1b = v1 + ((size_t)bt * Hh + w) * Rr * Dd;
#pragma unroll
    for (int mt = 0; mt < 2; mt++)
#pragma unroll
        for (int nt = 0; nt < 2; nt++)
#pragma unroll
            for (int reg = 0; reg < 4; reg++)
                atomicAdd(&v1b[(16 * mt + 4 * quad + reg) * 32 + 16 * nt + l15],
                          accV1[mt][nt][reg]);
}

// ---------------------------------------------------------------------------
// k2b: v1z[bt][h][d][r] = bf16( v1[bt][h][r][d] / Z[bt][h][r] )
// Transposed to [d][r] so r is contiguous (B-operand k-dim) for kb's v2 MFMA.
// ---------------------------------------------------------------------------
__global__ void k2b(const float* __restrict__ v1, const float* __restrict__ Z,
                    ushort* __restrict__ v1z)
{
    const int idx = blockIdx.x * 256 + threadIdx.x;   // ((bt*4+h)*32 + r)*32 + d
    const int d = idx & 31, r = (idx >> 5) & 31, hr = idx >> 10;
    const float z = Z[hr * 32 + r];
    v1z[((size_t)hr * 32 + d) * 32 + r] = f2bf(v1[idx] / z);
}

// ---------------------------------------------------------------------------
// kb (pass B): recompute attn (bit-identical to pass A: same bf16 inputs, same
// MFMA) and xv (hi/lo 3-term: this is the 0.9*xv precision-critical term),
// then v2 = expa @ v1z via MFMA (v1z L2-resident), out = sa*xv + sb*v2.
// Reads x (201 MB) + tiny; writes out (201 MB). expa never materialized.
// ---------------------------------------------------------------------------
__global__ __launch_bounds__(256, 2)
void kb(const float* __restrict__ x, const float* __restrict__ bv,
        const ushort* __restrict__ U, const float* __restrict__ bqk,
        const ushort* __restrict__ v1z, const float* __restrict__ alpha,
        const float* __restrict__ beta, float* __restrict__ out)
{
    // xhi [64][136] 17408 | xlo 17408 | 4x per-wave scratch 8192
    __shared__ __align__(16) char lds[67584];
    ushort* xhi = (ushort*)lds;
    ushort* xlo = (ushort*)(lds + 17408);

    const int t = threadIdx.x;
    const int w = t >> 6, lane = t & 63;
    const int quad = lane >> 4, l15 = lane & 15;
    const int bt = blockIdx.y;
    const int n0 = blockIdx.x * 64;

    char* wsc = lds + 34816 + w * 8192;
    ushort* eS = (ushort*)wsc;   // [64][40] bf16 expa (A-layout roundtrip)
    float*  fS = (float*)wsc;    // [64][32] f32 overlay (after eS reads; in-order DS)

    const float4* xg = (const float4*)(x + ((size_t)bt * Nn + n0) * Fc);
#pragma unroll
    for (int i = 0; i < 8; i++) {
        const int idx = i * 256 + t;
        const int row = idx >> 5, c4 = idx & 31;
        float4 v = xg[idx];
        ushort h0 = f2bf(v.x), h1 = f2bf(v.y), h2 = f2bf(v.z), h3 = f2bf(v.w);
        ushort4 hv; hv.x = h0; hv.y = h1; hv.z = h2; hv.w = h3;
        ushort4 lv; lv.x = f2bf(v.x - bf2f(h0)); lv.y = f2bf(v.y - bf2f(h1));
        lv.z = f2bf(v.z - bf2f(h2)); lv.w = f2bf(v.w - bf2f(h3));
        *(ushort4*)&xhi[row * 136 + c4 * 4] = hv;
        *(ushort4*)&xlo[row * 136 + c4 * 4] = lv;
    }
    __syncthreads();

    const ushort* WKh = U + U_WKHI;
    const ushort* Wvh = U + U_WVHI;
    const ushort* Wvl = U + U_WVLO;

    float bqkv[2], bvv[2];
#pragma unroll
    for (int i = 0; i < 2; i++) {
        bqkv[i] = bqk[32 * w + 16 * i + l15];
        bvv[i]  = bv[32 * w + 16 * i + l15];
    }

    floatx4 acca[4][2], accv[4][2];
#pragma unroll
    for (int mt = 0; mt < 4; mt++)
#pragma unroll
        for (int nt = 0; nt < 2; nt++) {
            acca[mt][nt] = (floatx4)0.f;
            accv[mt][nt] = (floatx4)0.f;
        }

#pragma unroll
    for (int kc = 0; kc < 4; kc++) {
        short8 ahi[4], alo[4];
#pragma unroll
        for (int mt = 0; mt < 4; mt++) {
            const int ro = (16 * mt + l15) * 136 + kc * 32 + quad * 8;
            ahi[mt] = *(const short8*)&xhi[ro];
            alo[mt] = *(const short8*)&xlo[ro];
        }
        short8 kb2[2], vbh[2], vbl[2];
#pragma unroll
        for (int nt = 0; nt < 2; nt++) {
            const int off = (32 * w + 16 * nt + l15) * 128 + kc * 32 + quad * 8;
            kb2[nt] = *(const short8*)&WKh[off];
            vbh[nt] = *(const short8*)&Wvh[off];
            vbl[nt] = *(const short8*)&Wvl[off];
        }
#pragma unroll
        for (int mt = 0; mt < 4; mt++)
#pragma unroll
            for (int nt = 0; nt < 2; nt++) {
                acca[mt][nt] = __builtin_amdgcn_mfma_f32_16x16x32_bf16(ahi[mt], kb2[nt], acca[mt][nt], 0, 0, 0);
                accv[mt][nt] = __builtin_amdgcn_mfma_f32_16x16x32_bf16(ahi[mt], vbh[nt], accv[mt][nt], 0, 0, 0);
                accv[mt][nt] = __builtin_amdgcn_mfma_f32_16x16x32_bf16(ahi[mt], vbl[nt], accv[mt][nt], 0, 0, 0);
                accv[mt][nt] = __builtin_amdgcn_mfma_f32_16x16x32_bf16(alo[mt], vbh[nt], accv[mt][nt], 0, 0, 0);
            }
    }

    // expa -> eS (C-layout -> A-layout roundtrip, per-wave in-order DS)
#pragma unroll
    for (int mt = 0; mt < 4; mt++)
#pragma unroll
        for (int rt = 0; rt < 2; rt++)
#pragma unroll
            for (int reg = 0; reg < 4; reg++) {
                const int row = 16 * mt + 4 * quad + reg;
                const int col = 16 * rt + l15;
                eS[row * 40 + col] =
                    f2bf(__expf((acca[mt][rt][reg] + bqkv[rt]) * SCALE));
            }

    // v2 = expa @ v1z  (A from eS, B from global v1z [d][r], L2-hot)
    short8 pa[4];
#pragma unroll
    for (int mt = 0; mt < 4; mt++)
        pa[mt] = *(const short8*)&eS[(16 * mt + l15) * 40 + quad * 8];
    short8 vbz[2];
#pragma unroll
    for (int dt = 0; dt < 2; dt++)
        vbz[dt] = *(const short8*)&v1z[(((size_t)bt * Hh + w) * Dd + 16 * dt + l15) * Rr + quad * 8];
    floatx4 acc2[4][2];
#pragma unroll
    for (int mt = 0; mt < 4; mt++)
#pragma unroll
        for (int dt = 0; dt < 2; dt++) {
            acc2[mt][dt] = (floatx4)0.f;
            acc2[mt][dt] = __builtin_amdgcn_mfma_f32_16x16x32_bf16(pa[mt], vbz[dt], acc2[mt][dt], 0, 0, 0);
        }

    const float sa = 1.f / (1.f + __expf(-alpha[w]));
    const float sb = 1.f / (1.f + __expf(-beta[w]));

    // out = sa*(xv+bv) + sb*v2 ; same C-layout for accv and acc2 -> direct mix,
    // then fS roundtrip (overlays eS after reads) for coalesced float4 stores
#pragma unroll
    for (int mt = 0; mt < 4; mt++)
#pragma unroll
        for (int nt = 0; nt < 2; nt++)
#pragma unroll
            for (int reg = 0; reg < 4; reg++) {
                const int row = 16 * mt + 4 * quad + reg;
                const int col = 16 * nt + l15;
                fS[row * 32 + col] =
                    sa * (accv[mt][nt][reg] + bvv[nt]) + sb * acc2[mt][nt][reg];
            }
#pragma unroll
    for (int i = 0; i < 8; i++) {
        const int idx = i * 64 + lane;
        const int n = idx >> 3, c4 = idx & 7;
        *(float4*)&out[((size_t)bt * Nn + n0 + n) * 128 + w * 32 + c4 * 4] =
            *(const float4*)&fS[n * 32 + c4 * 4];
    }
}

// ---------------------------------------------------------------------------
extern "C" void kernel_launch(void* const* d_in, const int* in_sizes, int n_in,
                              void* d_out, int out_size, void* d_ws, size_t ws_size,
                              hipStream_t stream)
{
    const float* x     = (const float*)d_in[0];
    const float* Wq    = (const float*)d_in[1];
    const float* bq    = (const float*)d_in[2];
    const float* key   = (const float*)d_in[3];
    const float* Wv    = (const float*)d_in[4];
    const float* bv    = (const float*)d_in[5];
    const float* alpha = (const float*)d_in[6];
    const float* beta  = (const float*)d_in[7];
    float* out = (float*)d_out;

    float*  ws   = (float*)d_ws;
    float*  v1   = ws + OFF_V1;
    float*  Z    = ws + OFF_Z;
    float*  bqkp = ws + OFF_BQK;
    ushort* v1z  = (ushort*)(ws + OFF_V1Z);
    ushort* U    = (ushort*)(ws + OFF_U);

    hipMemsetAsync(v1, 0,
                   (size_t)(BT * Hh * Rr * Dd + BT * Hh * Rr) * sizeof(float),
                   stream);
    kprep<<<dim3(129), 256, 0, stream>>>(Wq, bq, Wv, key, U, bqkp);
    ka<<<dim3(16, BT), 256, 0, stream>>>(x, bv, U, bqkp, v1, Z);
    k2b<<<dim3(BT * Hh * Rr * Dd / 256), 256, 0, stream>>>(v1, Z, v1z);
    kb<<<dim3(Nn / 64, BT), 256, 0, stream>>>(x, bv, U, bqkp, v1z, alpha, beta, out);
}

// Round 2
// 522.575 us; speedup vs baseline: 1.5015x; 1.0597x over previous
//
#include <hip/hip_runtime.h>

// Problem constants
constexpr int Nn = 4096, Fc = 128;
constexpr int Rr = 32, Hh = 4, Dd = 32;
constexpr int BT = 96;                          // B*T
constexpr float SCALE = 0.17677669529663687f;   // 1/sqrt(32)

// Workspace layout (float offsets)
constexpr size_t OFF_V1  = 0;                               // [BT][H][R][D] f32
constexpr size_t OFF_Z   = (size_t)BT * Hh * Rr * Dd;       // [BT][H][R]   f32
constexpr size_t OFF_BQK = OFF_Z + (size_t)BT * Hh * Rr;    // [H*R]        f32
constexpr size_t OFF_V1Z = OFF_BQK + 128;                   // [BT][H][D][R] bf16
constexpr size_t OFF_U   = OFF_V1Z + (size_t)BT * Hh * Dd * Rr / 2;

// U (ushort) offsets: WK hi (fused key·Wq), Wv hi, Wv lo
constexpr int U_WKHI = 0, U_WVHI = 16384, U_WVLO = 32768;

using short8  = __attribute__((ext_vector_type(8))) short;
using floatx4 = __attribute__((ext_vector_type(4))) float;

__device__ inline ushort f2bf(float f) {
    union { float f; unsigned u; } c{f};
    unsigned r = c.u + 0x7fffu + ((c.u >> 16) & 1u);  // RNE
    return (ushort)(r >> 16);
}
__device__ inline float bf2f(ushort u) {
    union { unsigned u; float f; } c{(unsigned)u << 16};
    return c.f;
}

// ---------------------------------------------------------------------------
// kprep: WK[h*32+r][f] = sum_d Wq[h*32+d][f]*key[r][h][d]  (bf16 hi)
//        Wv hi/lo split; bqk[h*32+r] = sum_d bq[h*32+d]*key[r][h][d] (f32)
// ---------------------------------------------------------------------------
__global__ void kprep(const float* __restrict__ Wq, const float* __restrict__ bq,
                      const float* __restrict__ Wv, const float* __restrict__ key,
                      ushort* __restrict__ U, float* __restrict__ bqk)
{
    const int idx = blockIdx.x * 256 + threadIdx.x;
    if (idx < 16384) {
        const int hr = idx >> 7, f = idx & 127;
        const int h = hr >> 5, r = hr & 31;
        float s = 0.f;
#pragma unroll
        for (int d = 0; d < 32; d++)
            s += Wq[(h * 32 + d) * 128 + f] * key[(r * 4 + h) * 32 + d];
        U[U_WKHI + idx] = f2bf(s);
    } else if (idx < 32768) {
        const int o = idx - 16384;
        const float v = Wv[o];
        const ushort h = f2bf(v);
        U[U_WVHI + o] = h;
        U[U_WVLO + o] = f2bf(v - bf2f(h));
    } else if (idx < 32768 + 128) {
        const int hr = idx - 32768;
        const int h = hr >> 5, r = hr & 31;
        float s = 0.f;
#pragma unroll
        for (int d = 0; d < 32; d++)
            s += bq[h * 32 + d] * key[(r * 4 + h) * 32 + d];
        bqk[hr] = s;
    }
}

// ---------------------------------------------------------------------------
// ka (pass A), software-pipelined: per block, NT=4 tiles of 64 nodes.
//   prologue: load tile0 -> regs
//   loop: regs->LDS(double buf), 1 sync, MFMA k-loop, ISSUE next tile loads,
//         epilogue (exp, transposes, rowsum butterfly, v1 MFMA) overlapping
//         the in-flight loads.
// Row-softmax 1/sum via 4-step shfl_xor butterfly (lane already holds its n's
// sum afterwards -> no LDS rowsum, no bpermute broadcast).
// ---------------------------------------------------------------------------
__global__ __launch_bounds__(256, 2)
void ka(const float* __restrict__ x, const float* __restrict__ bv,
        const ushort* __restrict__ U, const float* __restrict__ bqk,
        float* __restrict__ v1, float* __restrict__ Z)
{
    // xh x2 [64][136] bf16 (2*17408) | per-wave: eT [32][72], xvT [32][72]
    __shared__ __align__(16) char lds[71680];

    const int t = threadIdx.x;
    const int w = t >> 6, lane = t & 63;
    const int quad = lane >> 4, l15 = lane & 15;
    const int bt = blockIdx.y;
    constexpr int NT = 4;

    char* wsc = lds + 34816 + w * 9216;
    ushort* eT  = (ushort*)wsc;           // [32 r][72 n] bf16
    ushort* xvT = (ushort*)(wsc + 4608);  // [32 d][72 n] bf16 (xv*srw)

    const ushort* WKh = U + U_WKHI;
    const ushort* Wvh = U + U_WVHI;

    float bvv[2], bqkv[2];
#pragma unroll
    for (int i = 0; i < 2; i++) {
        bvv[i]  = bv[32 * w + 16 * i + l15];
        bqkv[i] = bqk[32 * w + 16 * i + l15];
    }

    floatx4 accV1[2][2];
#pragma unroll
    for (int i = 0; i < 2; i++)
#pragma unroll
        for (int j = 0; j < 2; j++) accV1[i][j] = (floatx4)0.f;
    float zacc[2] = {0.f, 0.f};

    const float* xbase = x + ((size_t)bt * Nn + blockIdx.x * (NT * 64)) * Fc;

    // prologue: tile 0 -> regs
    float4 xr[8];
#pragma unroll
    for (int i = 0; i < 8; i++) xr[i] = ((const float4*)xbase)[i * 256 + t];

#pragma unroll 1
    for (int it = 0; it < NT; ++it) {
        ushort* xh = (ushort*)(lds + (it & 1) * 17408);
        // regs -> LDS (waits on the prefetch issued last iteration)
#pragma unroll
        for (int i = 0; i < 8; i++) {
            const int idx = i * 256 + t;
            const int row = idx >> 5, c4 = idx & 31;
            float4 v = xr[i];
            ushort4 hv;
            hv.x = f2bf(v.x); hv.y = f2bf(v.y); hv.z = f2bf(v.z); hv.w = f2bf(v.w);
            *(ushort4*)&xh[row * 136 + c4 * 4] = hv;
        }
        __syncthreads();   // single barrier per iteration (double-buffered xh)

        floatx4 acca[4][2], accv[4][2];
#pragma unroll
        for (int mt = 0; mt < 4; mt++)
#pragma unroll
            for (int nt = 0; nt < 2; nt++) {
                acca[mt][nt] = (floatx4)0.f;
                accv[mt][nt] = (floatx4)0.f;
            }

#pragma unroll
        for (int kc = 0; kc < 4; kc++) {
            short8 ah[4];
#pragma unroll
            for (int mt = 0; mt < 4; mt++)
                ah[mt] = *(const short8*)&xh[(16 * mt + l15) * 136 + kc * 32 + quad * 8];
            short8 kb2[2], vb[2];
#pragma unroll
            for (int nt = 0; nt < 2; nt++) {
                const int off = (32 * w + 16 * nt + l15) * 128 + kc * 32 + quad * 8;
                kb2[nt] = *(const short8*)&WKh[off];
                vb[nt]  = *(const short8*)&Wvh[off];
            }
#pragma unroll
            for (int mt = 0; mt < 4; mt++)
#pragma unroll
                for (int nt = 0; nt < 2; nt++) {
                    acca[mt][nt] = __builtin_amdgcn_mfma_f32_16x16x32_bf16(ah[mt], kb2[nt], acca[mt][nt], 0, 0, 0);
                    accv[mt][nt] = __builtin_amdgcn_mfma_f32_16x16x32_bf16(ah[mt], vb[nt],  accv[mt][nt], 0, 0, 0);
                }
        }

        // issue next tile's loads NOW: they fly during the whole epilogue.
        // (after all weight loads, so no vmcnt FIFO entanglement)
        if (it + 1 < NT) {
            const float4* xg = (const float4*)(xbase + (size_t)(it + 1) * 64 * Fc);
#pragma unroll
            for (int i = 0; i < 8; i++) xr[i] = xg[i * 256 + t];
        }

        // exp -> eT bf16 [r][n]; Z partials; per-n rowsum partials in regs
        float sloc[4][4];
#pragma unroll
        for (int mt = 0; mt < 4; mt++)
#pragma unroll
            for (int reg = 0; reg < 4; reg++) {
                const int n = 16 * mt + 4 * quad + reg;
                const float e0 = __expf((acca[mt][0][reg] + bqkv[0]) * SCALE);
                const float e1 = __expf((acca[mt][1][reg] + bqkv[1]) * SCALE);
                eT[l15 * 72 + n]        = f2bf(e0);   // r = l15
                eT[(16 + l15) * 72 + n] = f2bf(e1);   // r = 16 + l15
                zacc[0] += e0; zacc[1] += e1;
                sloc[mt][reg] = e0 + e1;
            }
        // butterfly over the 16-lane group: sloc becomes sum_r e[n][r]
#pragma unroll
        for (int m = 1; m < 16; m <<= 1)
#pragma unroll
            for (int mt = 0; mt < 4; mt++)
#pragma unroll
                for (int reg = 0; reg < 4; reg++)
                    sloc[mt][reg] += __shfl_xor(sloc[mt][reg], m);

        // xv -> xvT [d][n] bf16, pre-scaled by 1/rowsum (lane owns its n's sum)
#pragma unroll
        for (int mt = 0; mt < 4; mt++)
#pragma unroll
            for (int reg = 0; reg < 4; reg++) {
                const int n = 16 * mt + 4 * quad + reg;
                const float sw = 1.f / sloc[mt][reg];
#pragma unroll
                for (int nt = 0; nt < 2; nt++)
                    xvT[(16 * nt + l15) * 72 + n] =
                        f2bf((accv[mt][nt][reg] + bvv[nt]) * sw);
            }

        // v1[r][d] += sum_n eT[r][n] * xvT[d][n]
#pragma unroll
        for (int kn = 0; kn < 2; kn++) {
            short8 ae[2], bx[2];
#pragma unroll
            for (int i = 0; i < 2; i++) {
                ae[i] = *(const short8*)&eT[(16 * i + l15) * 72 + kn * 32 + quad * 8];
                bx[i] = *(const short8*)&xvT[(16 * i + l15) * 72 + kn * 32 + quad * 8];
            }
#pragma unroll
            for (int mt = 0; mt < 2; mt++)
#pragma unroll
                for (int nt = 0; nt < 2; nt++)
                    accV1[mt][nt] = __builtin_amdgcn_mfma_f32_16x16x32_bf16(ae[mt], bx[nt], accV1[mt][nt], 0, 0, 0);
        }
    }

    // Z: reduce over quads, atomic once per col
#pragma unroll
    for (int rt = 0; rt < 2; rt++) {
        float zr = zacc[rt];
        zr += __shfl_xor(zr, 16);
        zr += __shfl_xor(zr, 32);
        if (quad == 0)
            atomicAdd(&Z[((size_t)bt * Hh + w) * Rr + 16 * rt + l15], zr);
    }
    float* v1b = v1 + ((size_t)bt * Hh + w) * Rr * Dd;
#pragma unroll
    for (int mt = 0; mt < 2; mt++)
#pragma unroll
        for (int nt = 0; nt < 2; nt++)
#pragma unroll
            for (int reg = 0; reg < 4; reg++)
                atomicAdd(&v1b[(16 * mt + 4 * quad + reg) * 32 + 16 * nt + l15],
                          accV1[mt][nt][reg]);
}

// ---------------------------------------------------------------------------
// k2b: v1z[bt][h][d][r] = bf16( v1[bt][h][r][d] / Z[bt][h][r] )
// ---------------------------------------------------------------------------
__global__ void k2b(const float* __restrict__ v1, const float* __restrict__ Z,
                    ushort* __restrict__ v1z)
{
    const int idx = blockIdx.x * 256 + threadIdx.x;
    const int d = idx & 31, r = (idx >> 5) & 31, hr = idx >> 10;
    const float z = Z[hr * 32 + r];
    v1z[((size_t)hr * 32 + d) * 32 + r] = f2bf(v1[idx] / z);
}

// ---------------------------------------------------------------------------
// kb (pass B), software-pipelined like ka: NT=4 tiles/block, register
// prefetch issued after the k-loop, in flight through the epilogue + stores.
// x stays hi/lo (xv is the precision-critical 0.9* term). Single-buffered
// x LDS (hi+lo won't fit doubled), so 2 syncs/iteration.
// ---------------------------------------------------------------------------
__global__ __launch_bounds__(256, 2)
void kb(const float* __restrict__ x, const float* __restrict__ bv,
        const ushort* __restrict__ U, const float* __restrict__ bqk,
        const ushort* __restrict__ v1z, const float* __restrict__ alpha,
        const float* __restrict__ beta, float* __restrict__ out)
{
    // xhi [64][136] 17408 | xlo 17408 | 4x per-wave scratch 8192
    __shared__ __align__(16) char lds[67584];
    ushort* xhi = (ushort*)lds;
    ushort* xlo = (ushort*)(lds + 17408);

    const int t = threadIdx.x;
    const int w = t >> 6, lane = t & 63;
    const int quad = lane >> 4, l15 = lane & 15;
    const int bt = blockIdx.y;
    constexpr int NT = 4;

    char* wsc = lds + 34816 + w * 8192;
    ushort* eS = (ushort*)wsc;   // [64][40] bf16
    float*  fS = (float*)wsc;    // [64][32] f32 overlay

    const ushort* WKh = U + U_WKHI;
    const ushort* Wvh = U + U_WVHI;
    const ushort* Wvl = U + U_WVLO;

    float bqkv[2], bvv[2];
#pragma unroll
    for (int i = 0; i < 2; i++) {
        bqkv[i] = bqk[32 * w + 16 * i + l15];
        bvv[i]  = bv[32 * w + 16 * i + l15];
    }
    // tile-invariant hoists: v1z B-frag, gate scalars
    short8 vbz[2];
#pragma unroll
    for (int dt = 0; dt < 2; dt++)
        vbz[dt] = *(const short8*)&v1z[(((size_t)bt * Hh + w) * Dd + 16 * dt + l15) * Rr + quad * 8];
    const float sa = 1.f / (1.f + __expf(-alpha[w]));
    const float sb = 1.f / (1.f + __expf(-beta[w]));

    const float* xbase = x + ((size_t)bt * Nn + blockIdx.x * (NT * 64)) * Fc;
    float* obase = out + ((size_t)bt * Nn + blockIdx.x * (NT * 64)) * Fc;

    float4 xr[8];
#pragma unroll
    for (int i = 0; i < 8; i++) xr[i] = ((const float4*)xbase)[i * 256 + t];

#pragma unroll 1
    for (int it = 0; it < NT; ++it) {
        // regs -> LDS hi/lo (waits on prefetch)
#pragma unroll
        for (int i = 0; i < 8; i++) {
            const int idx = i * 256 + t;
            const int row = idx >> 5, c4 = idx & 31;
            float4 v = xr[i];
            ushort h0 = f2bf(v.x), h1 = f2bf(v.y), h2 = f2bf(v.z), h3 = f2bf(v.w);
            ushort4 hv; hv.x = h0; hv.y = h1; hv.z = h2; hv.w = h3;
            ushort4 lv; lv.x = f2bf(v.x - bf2f(h0)); lv.y = f2bf(v.y - bf2f(h1));
            lv.z = f2bf(v.z - bf2f(h2)); lv.w = f2bf(v.w - bf2f(h3));
            *(ushort4*)&xhi[row * 136 + c4 * 4] = hv;
            *(ushort4*)&xlo[row * 136 + c4 * 4] = lv;
        }
        __syncthreads();

        floatx4 acca[4][2], accv[4][2];
#pragma unroll
        for (int mt = 0; mt < 4; mt++)
#pragma unroll
            for (int nt = 0; nt < 2; nt++) {
                acca[mt][nt] = (floatx4)0.f;
                accv[mt][nt] = (floatx4)0.f;
            }

#pragma unroll
        for (int kc = 0; kc < 4; kc++) {
            short8 ahi[4], alo[4];
#pragma unroll
            for (int mt = 0; mt < 4; mt++) {
                const int ro = (16 * mt + l15) * 136 + kc * 32 + quad * 8;
                ahi[mt] = *(const short8*)&xhi[ro];
                alo[mt] = *(const short8*)&xlo[ro];
            }
            short8 kb2[2], vbh[2], vbl[2];
#pragma unroll
            for (int nt = 0; nt < 2; nt++) {
                const int off = (32 * w + 16 * nt + l15) * 128 + kc * 32 + quad * 8;
                kb2[nt] = *(const short8*)&WKh[off];
                vbh[nt] = *(const short8*)&Wvh[off];
                vbl[nt] = *(const short8*)&Wvl[off];
            }
#pragma unroll
            for (int mt = 0; mt < 4; mt++)
#pragma unroll
                for (int nt = 0; nt < 2; nt++) {
                    acca[mt][nt] = __builtin_amdgcn_mfma_f32_16x16x32_bf16(ahi[mt], kb2[nt], acca[mt][nt], 0, 0, 0);
                    accv[mt][nt] = __builtin_amdgcn_mfma_f32_16x16x32_bf16(ahi[mt], vbh[nt], accv[mt][nt], 0, 0, 0);
                    accv[mt][nt] = __builtin_amdgcn_mfma_f32_16x16x32_bf16(ahi[mt], vbl[nt], accv[mt][nt], 0, 0, 0);
                    accv[mt][nt] = __builtin_amdgcn_mfma_f32_16x16x32_bf16(alo[mt], vbh[nt], accv[mt][nt], 0, 0, 0);
                }
        }

        // issue next tile's loads: in flight through the whole epilogue
        if (it + 1 < NT) {
            const float4* xg = (const float4*)(xbase + (size_t)(it + 1) * 64 * Fc);
#pragma unroll
            for (int i = 0; i < 8; i++) xr[i] = xg[i * 256 + t];
        }

        // expa -> eS (C-layout -> A-layout roundtrip, per-wave in-order DS)
#pragma unroll
        for (int mt = 0; mt < 4; mt++)
#pragma unroll
            for (int rt = 0; rt < 2; rt++)
#pragma unroll
                for (int reg = 0; reg < 4; reg++) {
                    const int row = 16 * mt + 4 * quad + reg;
                    const int col = 16 * rt + l15;
                    eS[row * 40 + col] =
                        f2bf(__expf((acca[mt][rt][reg] + bqkv[rt]) * SCALE));
                }

        // v2 = expa @ v1z
        short8 pa[4];
#pragma unroll
        for (int mt = 0; mt < 4; mt++)
            pa[mt] = *(const short8*)&eS[(16 * mt + l15) * 40 + quad * 8];
        floatx4 acc2[4][2];
#pragma unroll
        for (int mt = 0; mt < 4; mt++)
#pragma unroll
            for (int dt = 0; dt < 2; dt++) {
                acc2[mt][dt] = (floatx4)0.f;
                acc2[mt][dt] = __builtin_amdgcn_mfma_f32_16x16x32_bf16(pa[mt], vbz[dt], acc2[mt][dt], 0, 0, 0);
            }

        // out = sa*(xv+bv) + sb*v2 via fS roundtrip for coalesced stores
#pragma unroll
        for (int mt = 0; mt < 4; mt++)
#pragma unroll
            for (int nt = 0; nt < 2; nt++)
#pragma unroll
                for (int reg = 0; reg < 4; reg++) {
                    const int row = 16 * mt + 4 * quad + reg;
                    const int col = 16 * nt + l15;
                    fS[row * 32 + col] =
                        sa * (accv[mt][nt][reg] + bvv[nt]) + sb * acc2[mt][nt][reg];
                }
        float* op = obase + (size_t)it * 64 * Fc;
#pragma unroll
        for (int i = 0; i < 8; i++) {
            const int idx = i * 64 + lane;
            const int n = idx >> 3, c4 = idx & 7;
            *(float4*)&op[(size_t)n * 128 + w * 32 + c4 * 4] =
                *(const float4*)&fS[n * 32 + c4 * 4];
        }
        __syncthreads();   // xhi/xlo reads done before next overwrite
    }
}

// ---------------------------------------------------------------------------
extern "C" void kernel_launch(void* const* d_in, const int* in_sizes, int n_in,
                              void* d_out, int out_size, void* d_ws, size_t ws_size,
                              hipStream_t stream)
{
    const float* x     = (const float*)d_in[0];
    const float* Wq    = (const float*)d_in[1];
    const float* bq    = (const float*)d_in[2];
    const float* key   = (const float*)d_in[3];
    const float* Wv    = (const float*)d_in[4];
    const float* bv    = (const float*)d_in[5];
    const float* alpha = (const float*)d_in[6];
    const float* beta  = (const float*)d_in[7];
    float* out = (float*)d_out;

    float*  ws   = (float*)d_ws;
    float*  v1   = ws + OFF_V1;
    float*  Z    = ws + OFF_Z;
    float*  bqkp = ws + OFF_BQK;
    ushort* v1z  = (ushort*)(ws + OFF_V1Z);
    ushort* U    = (ushort*)(ws + OFF_U);

    hipMemsetAsync(v1, 0,
                   (size_t)(BT * Hh * Rr * Dd + BT * Hh * Rr) * sizeof(float),
                   stream);
    kprep<<<dim3(129), 256, 0, stream>>>(Wq, bq, Wv, key, U, bqkp);
    ka<<<dim3(16, BT), 256, 0, stream>>>(x, bv, U, bqkp, v1, Z);
    k2b<<<dim3(BT * Hh * Rr * Dd / 256), 256, 0, stream>>>(v1, Z, v1z);
    kb<<<dim3(16, BT), 256, 0, stream>>>(x, bv, U, bqkp, v1z, alpha, beta, out);
}